// Round 6
// baseline (133.045 us; speedup 1.0000x reference)
//
#include <hip/hip_runtime.h>
#include <hip/hip_fp16.h>
#include <cstddef>

// N=8, C=128, L=512, D=64, F=512, ATTN_W=64

// ---------------------------------------------------------------------------
// Kernel 1: prep = q/k projection only. grid 256, block 512.
// Block = (n, l-tile of 16). Half 0 (tid<256): q via Wt; half 1: k via Wx.
// ---------------------------------------------------------------------------
__global__ __launch_bounds__(512) void prep_kernel(
    const float* __restrict__ x, const float* __restrict__ Wt,
    const float* __restrict__ Wx, float* __restrict__ q,
    float* __restrict__ k) {
  __shared__ float xs[128][17];
  int tid = threadIdx.x;
  int n = blockIdx.x >> 5;
  int l0 = (blockIdx.x & 31) << 4;

  {  // stage x tile: 128 c x 16 l  (512 float4 tasks, one per thread)
    int c = tid >> 2, v = tid & 3;
    float4 d4 = *(const float4*)(x + ((size_t)n * 128 + c) * 512 + l0 + 4 * v);
    xs[c][4 * v + 0] = d4.x; xs[c][4 * v + 1] = d4.y;
    xs[c][4 * v + 2] = d4.z; xs[c][4 * v + 3] = d4.w;
  }
  __syncthreads();

  int half = tid >> 8;       // 0: q/Wt, 1: k/Wx
  int t = tid & 255;
  int r = t >> 4;            // 0..15
  int f0 = (t & 15) << 2;    // 0..60
  const float* W = half ? Wx : Wt;
  float* dst = half ? k : q;
  float acc[4] = {0.f, 0.f, 0.f, 0.f};
#pragma unroll 4
  for (int cc = 0; cc < 128; cc++) {
    float xv = xs[cc][r];
    float4 w = *(const float4*)(W + cc * 64 + f0);
    acc[0] += xv * w.x; acc[1] += xv * w.y;
    acc[2] += xv * w.z; acc[3] += xv * w.w;
  }
  *(float4*)(dst + ((size_t)n * 512 + l0 + r) * 64 + f0) =
      make_float4(acc[0], acc[1], acc[2], acc[3]);
}

// ---------------------------------------------------------------------------
// Kernel 2: FUSED attn+FFN. 8 rows/block, grid 512, block 512 (8 waves).
// LDS cut to 54.4 KB -> 3 blocks/CU = 6 waves/SIMD: decorrelates the
// barrier-lockstep stalls that pinned the kernel at ~42.5 us.
//   - x-window fp16 (19.5 KB vs 39.4); residual kept exact in fp32 xres
//   - part[8][8][128] time-aliased onto dead tstT region (extra barrier)
//   - ys eliminated (LN1 written back into xstT, per-thread RMW-safe)
// ---------------------------------------------------------------------------
__global__ __launch_bounds__(512, 6) void attn_ffn_fused_kernel(
    const float* __restrict__ x, const float* __restrict__ q,
    const float* __restrict__ k, const float* __restrict__ bh,
    const float* __restrict__ Wa, const float* __restrict__ ba,
    const float* __restrict__ g0, const float* __restrict__ be0,
    const float* __restrict__ W0, const float* __restrict__ b0,
    const float* __restrict__ W1, const float* __restrict__ b1,
    const float* __restrict__ g1, const float* __restrict__ be1,
    float* __restrict__ a, float* __restrict__ out) {
  // Aliased region (45456 B):
  //  Phases A/B: ks[71][68] @0 (19312), qs[8][64] @19312 (2048),
  //              xtw half[128*78] @21360 (19968), xres[8][129] @41328 (4128)
  //  Phase C:    tstT[512][12] @0 (24576)
  //  Phase C2+:  part[8][8][128] @0 (32768)   [after barrier; tstT dead]
  __shared__ __align__(16) char smem[45456];
  __shared__ __align__(16) float xstT[128][12];  // x2 tile [c][r]
  __shared__ float avT[71][9];                   // [abs_col][row], stride 9
  __shared__ float was[64];

  float (*ks)[68] = (float(*)[68])smem;              // [71][68]
  float (*qs)[64] = (float(*)[64])(smem + 19312);    // [8][64]
  __half* xtw = (__half*)(smem + 21360);             // [128][78] halves
  float (*xres)[129] = (float(*)[129])(smem + 41328);  // [8][129]
  float (*tstT)[12] = (float(*)[12])smem;            // [512][12]
  float (*part)[8][128] = (float(*)[8][128])smem;    // [8][8][128]

  int tid = threadIdx.x;
  int w = tid >> 6, lane = tid & 63;
  // XCD-aware bijective swizzle (gridDim 512 % 8 == 0)
  int bid = blockIdx.x;
  int tile = (bid & 7) * 64 + (bid >> 3);
  size_t rbase = (size_t)tile * 8;
  int n = (int)(rbase >> 9);
  int i0 = (int)(rbase & 511);
  int jlo0 = i0 - 32;

  // ---- Phase A: stage q(+bh), k-window, x-window(fp16)+xres; zero avT ----
  if (tid < 64) was[tid] = Wa[tid];
  for (int idx = tid; idx < 71 * 9; idx += 512) ((float*)avT)[idx] = 0.f;
  if (tid < 128) {
    int r = tid >> 4, d4 = (tid & 15) << 2;
    float4 qv = *(const float4*)(q + ((size_t)n * 512 + i0 + r) * 64 + d4);
    float4 bv = *(const float4*)(bh + d4);
    *(float4*)(&qs[r][d4]) =
        make_float4(qv.x + bv.x, qv.y + bv.y, qv.z + bv.z, qv.w + bv.w);
  }
  for (int idx = tid; idx < 71 * 16; idx += 512) {
    int row = idx >> 4, d4 = (idx & 15) << 2;
    int j = jlo0 + row;
    float4 v = make_float4(0.f, 0.f, 0.f, 0.f);
    if (j >= 0 && j < 512)
      v = *(const float4*)(k + ((size_t)n * 512 + j) * 64 + d4);
    *(float4*)(&ks[row][d4]) = v;
  }
  // x-window fp16: 128 c x 18 float4-chunks; center cols 32..39 also fp32
  for (int t = tid; t < 128 * 18; t += 512) {
    int c = t / 18;
    int u = t - c * 18;
    int col = 4 * u;
    int j0 = jlo0 + col;
    const float* xp = x + ((size_t)n * 128 + c) * 512;
    float4 v = make_float4(0.f, 0.f, 0.f, 0.f);
    if (j0 >= 0 && j0 + 3 < 512) {
      v = *(const float4*)(xp + j0);
    } else {
      if (j0 + 0 >= 0 && j0 + 0 < 512) v.x = xp[j0 + 0];
      if (j0 + 1 >= 0 && j0 + 1 < 512) v.y = xp[j0 + 1];
      if (j0 + 2 >= 0 && j0 + 2 < 512) v.z = xp[j0 + 2];
      if (j0 + 3 >= 0 && j0 + 3 < 512) v.w = xp[j0 + 3];
    }
    __half2 p01, p23;
    p01.x = __float2half(v.x); p01.y = __float2half(v.y);
    p23.x = __float2half(v.z); p23.y = __float2half(v.w);
    *(__half2*)(xtw + c * 78 + col) = p01;
    *(__half2*)(xtw + c * 78 + col + 2) = p23;
    if (u == 8 || u == 9) {  // residual columns, exact fp32
      int r0x = col - 32;
      xres[r0x + 0][c] = v.x; xres[r0x + 1][c] = v.y;
      xres[r0x + 2][c] = v.z; xres[r0x + 3][c] = v.w;
    }
  }
  __syncthreads();

  // ---- Phase A2: scores + softmax + a-write. Wave w -> row w ----
  {
    int r = w;
    int i = i0 + r;
    int j = jlo0 + r + lane;
    bool valid = (j >= 0 && j < 512);
    const float* krow = &ks[r + lane][0];  // stride 68: conflict-free f4
    float e = 0.f;
#pragma unroll
    for (int d4 = 0; d4 < 64; d4 += 4) {
      float4 kv = *(const float4*)(krow + d4);
      float4 qv = *(const float4*)(&qs[r][d4]);
      float4 wv = *(const float4*)(&was[d4]);
      float h0 = qv.x + kv.x, h1 = qv.y + kv.y;
      float h2 = qv.z + kv.z, h3 = qv.w + kv.w;
      float t0 = 1.f - 2.f * __builtin_amdgcn_rcpf(__expf(2.f * h0) + 1.f);
      float t1 = 1.f - 2.f * __builtin_amdgcn_rcpf(__expf(2.f * h1) + 1.f);
      float t2 = 1.f - 2.f * __builtin_amdgcn_rcpf(__expf(2.f * h2) + 1.f);
      float t3 = 1.f - 2.f * __builtin_amdgcn_rcpf(__expf(2.f * h3) + 1.f);
      e += wv.x * t0 + wv.y * t1 + wv.z * t2 + wv.w * t3;
    }
    e += ba[0];
    if (!valid) e = -1e30f;

    float m = e;
    for (int o = 32; o > 0; o >>= 1) m = fmaxf(m, __shfl_xor(m, o, 64));
    float ex = valid ? __expf(e - m) : 0.f;
    float s = ex;
    for (int o = 32; o > 0; o >>= 1) s += __shfl_xor(s, o, 64);
    avT[r + lane][r] = ex / (s + 1e-6f);  // abs col = r + lane

    float* arow = a + ((size_t)n * 512 + i) * 512;
    int jlo = i - 32;
#pragma unroll
    for (int t = 0; t < 2; t++) {
      int col0 = 4 * lane + 256 * t;
      float4 v;
      { int jr = col0 + 0 - jlo; int jc = min(max(jr, 0), 63); v.x = (jr >= 0 && jr < 64) ? avT[r + jc][r] : 0.f; }
      { int jr = col0 + 1 - jlo; int jc = min(max(jr, 0), 63); v.y = (jr >= 0 && jr < 64) ? avT[r + jc][r] : 0.f; }
      { int jr = col0 + 2 - jlo; int jc = min(max(jr, 0), 63); v.z = (jr >= 0 && jr < 64) ? avT[r + jc][r] : 0.f; }
      { int jr = col0 + 3 - jlo; int jc = min(max(jr, 0), 63); v.w = (jr >= 0 && jr < 64) ? avT[r + jc][r] : 0.f; }
      *(float4*)(arow + col0) = v;
    }
  }
  __syncthreads();

  // ---- Phase B: v = a@x + residual -> xstT[c][r] (all-LDS) ----
  {
    int c = tid & 127;
    int r0 = (tid >> 7) << 1;  // 0,2,4,6 -> rows r0, r0+1
    const __half* xr = xtw + c * 78;
    float acc0 = 0.f, acc1 = 0.f;
#pragma unroll 5
    for (int m = 0; m < 65; m++) {
      int col = r0 + m;
      float xv = __half2float(xr[col]);  // u16, ~2-way: free
      float a0 = avT[col][r0];           // broadcast
      float a1 = avT[col][r0 + 1];       // broadcast
      acc0 += a0 * xv;
      acc1 += a1 * xv;
    }
    float res0 = xres[r0][c];
    float res1 = xres[r0 + 1][c];
    *(float2*)(&xstT[c][r0]) = make_float2(acc0 + res0, acc1 + res1);
  }
  __syncthreads();

  // ---- Phase B2: LN0 in place on xstT. Wave w -> row w ----
  {
    float a0 = xstT[lane][w], a1 = xstT[lane + 64][w];
    float s = a0 + a1, s2 = a0 * a0 + a1 * a1;
    for (int o = 32; o > 0; o >>= 1) {
      s += __shfl_xor(s, o, 64);
      s2 += __shfl_xor(s2, o, 64);
    }
    float mu = s * (1.f / 128.f);
    float var = s2 * (1.f / 128.f) - mu * mu;
    float rs = rsqrtf(var + 1e-5f);
    xstT[lane][w] = (a0 - mu) * rs * g0[lane] + be0[lane];
    xstT[lane + 64][w] = (a1 - mu) * rs * g0[lane + 64] + be0[lane + 64];
  }
  __syncthreads();

  // ---- Phase C: GEMM1 (in-wave 4-way K-split, 4-deep W prefetch) ----
  {
    int g = lane & 15;   // f4-group within wave
    int kq = lane >> 4;  // K-quarter 0..3
    int f0 = (16 * w + g) << 2;
    int ccb = kq << 5;
    const float* w0p = W0 + (size_t)ccb * 512 + f0;
    float acc[8][4];
#pragma unroll
    for (int i = 0; i < 8; i++)
#pragma unroll
      for (int u = 0; u < 4; u++) acc[i][u] = 0.f;

    float4 wbuf[4];
#pragma unroll
    for (int p = 0; p < 4; p++)
      wbuf[p] = *(const float4*)(w0p + (size_t)p * 512);
#pragma unroll
    for (int c4 = 0; c4 < 8; c4++) {
      float4 cur0 = wbuf[0], cur1 = wbuf[1], cur2 = wbuf[2], cur3 = wbuf[3];
      if (c4 < 7) {
#pragma unroll
        for (int p = 0; p < 4; p++)
          wbuf[p] = *(const float4*)(w0p + (size_t)((c4 + 1) * 4 + p) * 512);
      }
#pragma unroll
      for (int p = 0; p < 4; p++) {
        int cc = ccb + c4 * 4 + p;
        float4 wv = (p == 0) ? cur0 : (p == 1) ? cur1 : (p == 2) ? cur2 : cur3;
        float4 xa = *(const float4*)(&xstT[cc][0]);  // broadcast
        float4 xb = *(const float4*)(&xstT[cc][4]);
        acc[0][0] += xa.x * wv.x; acc[0][1] += xa.x * wv.y; acc[0][2] += xa.x * wv.z; acc[0][3] += xa.x * wv.w;
        acc[1][0] += xa.y * wv.x; acc[1][1] += xa.y * wv.y; acc[1][2] += xa.y * wv.z; acc[1][3] += xa.y * wv.w;
        acc[2][0] += xa.z * wv.x; acc[2][1] += xa.z * wv.y; acc[2][2] += xa.z * wv.z; acc[2][3] += xa.z * wv.w;
        acc[3][0] += xa.w * wv.x; acc[3][1] += xa.w * wv.y; acc[3][2] += xa.w * wv.z; acc[3][3] += xa.w * wv.w;
        acc[4][0] += xb.x * wv.x; acc[4][1] += xb.x * wv.y; acc[4][2] += xb.x * wv.z; acc[4][3] += xb.x * wv.w;
        acc[5][0] += xb.y * wv.x; acc[5][1] += xb.y * wv.y; acc[5][2] += xb.y * wv.z; acc[5][3] += xb.y * wv.w;
        acc[6][0] += xb.z * wv.x; acc[6][1] += xb.z * wv.y; acc[6][2] += xb.z * wv.z; acc[6][3] += xb.z * wv.w;
        acc[7][0] += xb.w * wv.x; acc[7][1] += xb.w * wv.y; acc[7][2] += xb.w * wv.z; acc[7][3] += xb.w * wv.w;
      }
    }
    // butterfly-reduce over kq (lane bits 4,5)
#pragma unroll
    for (int i = 0; i < 8; i++)
#pragma unroll
      for (int u = 0; u < 4; u++) {
        float v = acc[i][u];
        v += __shfl_xor(v, 16, 64);
        v += __shfl_xor(v, 32, 64);
        acc[i][u] = v;
      }
    int f = f0 + kq;
    float bb = b0[f];
    float r0v[8];
#pragma unroll
    for (int i = 0; i < 8; i++) {
      float v = (kq == 0) ? acc[i][0] : (kq == 1) ? acc[i][1]
              : (kq == 2) ? acc[i][2] : acc[i][3];
      r0v[i] = fmaxf(v + bb, 0.f);
    }
    *(float4*)(&tstT[f][0]) = make_float4(r0v[0], r0v[1], r0v[2], r0v[3]);
    *(float4*)(&tstT[f][4]) = make_float4(r0v[4], r0v[5], r0v[6], r0v[7]);
  }
  __syncthreads();

  // ---- Phase C2: GEMM2 (wave = K-octile, 4-deep W prefetch), acc in regs ----
  float g2acc[4][4];
  {
    int c0 = (lane & 31) << 2;
    int rh = lane >> 5;  // 0..1 -> rows 4rh..4rh+3
    const float* W1p = W1 + (size_t)w * 64 * 128 + c0;
    int tb = w << 6;
#pragma unroll
    for (int i = 0; i < 4; i++)
#pragma unroll
      for (int u = 0; u < 4; u++) g2acc[i][u] = 0.f;

    float4 wbuf[4];
#pragma unroll
    for (int p = 0; p < 4; p++)
      wbuf[p] = *(const float4*)(W1p + (size_t)p * 128);
#pragma unroll
    for (int t4 = 0; t4 < 16; t4++) {
      float4 cur0 = wbuf[0], cur1 = wbuf[1], cur2 = wbuf[2], cur3 = wbuf[3];
      if (t4 < 15) {
#pragma unroll
        for (int p = 0; p < 4; p++)
          wbuf[p] = *(const float4*)(W1p + (size_t)((t4 + 1) * 4 + p) * 128);
      }
#pragma unroll
      for (int p = 0; p < 4; p++) {
        int t = t4 * 4 + p;
        float4 wv = (p == 0) ? cur0 : (p == 1) ? cur1 : (p == 2) ? cur2 : cur3;
        float4 tv = *(const float4*)(&tstT[tb + t][4 * rh]);  // 2-addr bcast
        g2acc[0][0] += tv.x * wv.x; g2acc[0][1] += tv.x * wv.y; g2acc[0][2] += tv.x * wv.z; g2acc[0][3] += tv.x * wv.w;
        g2acc[1][0] += tv.y * wv.x; g2acc[1][1] += tv.y * wv.y; g2acc[1][2] += tv.y * wv.z; g2acc[1][3] += tv.y * wv.w;
        g2acc[2][0] += tv.z * wv.x; g2acc[2][1] += tv.z * wv.y; g2acc[2][2] += tv.z * wv.z; g2acc[2][3] += tv.z * wv.w;
        g2acc[3][0] += tv.w * wv.x; g2acc[3][1] += tv.w * wv.y; g2acc[3][2] += tv.w * wv.z; g2acc[3][3] += tv.w * wv.w;
      }
    }
  }
  __syncthreads();  // tstT reads done by ALL waves -> part may overwrite

  {
    int c0 = (lane & 31) << 2;
    int rh = lane >> 5;
#pragma unroll
    for (int i = 0; i < 4; i++) {
      *(float4*)(&part[w][4 * rh + i][c0]) =
          make_float4(g2acc[i][0], g2acc[i][1], g2acc[i][2], g2acc[i][3]);
    }
  }
  __syncthreads();

  // ---- merged combine + bias + residual + LN1 -> back into xstT ----
  {
    float a0 = b1[lane] + xstT[lane][w];
    float a1 = b1[lane + 64] + xstT[lane + 64][w];
#pragma unroll
    for (int ko = 0; ko < 8; ko++) {
      a0 += part[ko][w][lane];        // conflict-free b32
      a1 += part[ko][w][lane + 64];
    }
    float s = a0 + a1, s2 = a0 * a0 + a1 * a1;
    for (int o = 32; o > 0; o >>= 1) {
      s += __shfl_xor(s, o, 64);
      s2 += __shfl_xor(s2, o, 64);
    }
    float mu = s * (1.f / 128.f);
    float var = s2 * (1.f / 128.f) - mu * mu;
    float rs = rsqrtf(var + 1e-5f);
    xstT[lane][w] = (a0 - mu) * rs * g1[lane] + be1[lane];       // RMW own slot
    xstT[lane + 64][w] = (a1 - mu) * rs * g1[lane + 64] + be1[lane + 64];
  }
  __syncthreads();

  // ---- transposed write: out (N,C,L); 8 consecutive l per c ----
  {
    int c = tid >> 2, tq = tid & 3;
    *(float2*)(out + ((size_t)n * 128 + c) * 512 + i0 + 2 * tq) =
        make_float2(xstT[c][2 * tq], xstT[c][2 * tq + 1]);
  }
}

// ---------------------------------------------------------------------------
extern "C" void kernel_launch(void* const* d_in, const int* in_sizes, int n_in,
                              void* d_out, int out_size, void* d_ws, size_t ws_size,
                              hipStream_t stream) {
  const float* x   = (const float*)d_in[0];
  const float* Wx  = (const float*)d_in[1];
  const float* Wt  = (const float*)d_in[2];
  const float* bh  = (const float*)d_in[3];
  const float* Wa  = (const float*)d_in[4];
  const float* ba  = (const float*)d_in[5];
  const float* W0  = (const float*)d_in[6];
  const float* b0  = (const float*)d_in[7];
  const float* W1  = (const float*)d_in[8];
  const float* b1  = (const float*)d_in[9];
  const float* g0  = (const float*)d_in[10];
  const float* be0 = (const float*)d_in[11];
  const float* g1  = (const float*)d_in[12];
  const float* be1 = (const float*)d_in[13];

  float* outx = (float*)d_out;           // N*C*L = 524288
  float* outa = outx + (size_t)524288;   // N*L*L = 2097152

  float* ws = (float*)d_ws;
  float* q  = ws;              // 262144
  float* k  = q + 262144;      // 262144

  prep_kernel<<<256, 512, 0, stream>>>(x, Wt, Wx, q, k);
  attn_ffn_fused_kernel<<<512, 512, 0, stream>>>(
      x, q, k, bh, Wa, ba, g0, be0, W0, b0, W1, b1, g1, be1, outa, outx);
}

// Round 7
// 128.001 us; speedup vs baseline: 1.0394x; 1.0394x over previous
//
#include <hip/hip_runtime.h>
#include <hip/hip_fp16.h>
#include <cstddef>

// N=8, C=128, L=512, D=64, F=512, ATTN_W=64

// ---------------------------------------------------------------------------
// Kernel 1: prep = q/k projection only. grid 256, block 512.
// Block = (n, l-tile of 16). Half 0 (tid<256): q via Wt; half 1: k via Wx.
// ---------------------------------------------------------------------------
__global__ __launch_bounds__(512) void prep_kernel(
    const float* __restrict__ x, const float* __restrict__ Wt,
    const float* __restrict__ Wx, float* __restrict__ q,
    float* __restrict__ k) {
  __shared__ float xs[128][17];
  int tid = threadIdx.x;
  int n = blockIdx.x >> 5;
  int l0 = (blockIdx.x & 31) << 4;

  {  // stage x tile: 128 c x 16 l  (512 float4 tasks, one per thread)
    int c = tid >> 2, v = tid & 3;
    float4 d4 = *(const float4*)(x + ((size_t)n * 128 + c) * 512 + l0 + 4 * v);
    xs[c][4 * v + 0] = d4.x; xs[c][4 * v + 1] = d4.y;
    xs[c][4 * v + 2] = d4.z; xs[c][4 * v + 3] = d4.w;
  }
  __syncthreads();

  int half = tid >> 8;       // 0: q/Wt, 1: k/Wx
  int t = tid & 255;
  int r = t >> 4;            // 0..15
  int f0 = (t & 15) << 2;    // 0..60
  const float* W = half ? Wx : Wt;
  float* dst = half ? k : q;
  float acc[4] = {0.f, 0.f, 0.f, 0.f};
#pragma unroll 4
  for (int cc = 0; cc < 128; cc++) {
    float xv = xs[cc][r];
    float4 w = *(const float4*)(W + cc * 64 + f0);
    acc[0] += xv * w.x; acc[1] += xv * w.y;
    acc[2] += xv * w.z; acc[3] += xv * w.w;
  }
  *(float4*)(dst + ((size_t)n * 512 + l0 + r) * 64 + f0) =
      make_float4(acc[0], acc[1], acc[2], acc[3]);
}

// ---------------------------------------------------------------------------
// Kernel 2: FUSED attn+FFN. 8 rows/block, grid 512, block 512 (8 waves).
// LDS 50284 B -> 3 blocks/CU (151 KB < 160 KB) at VGPR 64 (launch_bounds
// min kept at 4 waves/EU so the allocator is NOT squeezed -- R6's (512,6)
// forced VGPR 40 and spilled; occupancy is decided at dispatch by actual
// resources, so 3 blocks/CU follows from the LDS cut alone).
//   - x-window fp16 (19.5 KB); residual read exact from L2-hot global x
//   - part[8][8][128] time-aliased onto dead tstT region (extra barrier)
//   - ys eliminated (LN1 written back into xstT, per-thread RMW-safe)
// ---------------------------------------------------------------------------
__global__ __launch_bounds__(512, 4) void attn_ffn_fused_kernel(
    const float* __restrict__ x, const float* __restrict__ q,
    const float* __restrict__ k, const float* __restrict__ bh,
    const float* __restrict__ Wa, const float* __restrict__ ba,
    const float* __restrict__ g0, const float* __restrict__ be0,
    const float* __restrict__ W0, const float* __restrict__ b0,
    const float* __restrict__ W1, const float* __restrict__ b1,
    const float* __restrict__ g1, const float* __restrict__ be1,
    float* __restrict__ a, float* __restrict__ out) {
  // Aliased region (41328 B):
  //  Phases A/B: ks[71][68] @0 (19312), qs[8][64] @19312 (2048),
  //              xtw half[128*78] @21360 (19968)
  //  Phase C:    tstT[512][12] @0 (24576)
  //  Phase C2+:  part[8][8][128] @0 (32768)   [after barrier; tstT dead]
  __shared__ __align__(16) char smem[41328];
  __shared__ __align__(16) float xstT[128][12];  // x2 tile [c][r]
  __shared__ float avT[71][9];                   // [abs_col][row], stride 9
  __shared__ float was[64];

  float (*ks)[68] = (float(*)[68])smem;              // [71][68]
  float (*qs)[64] = (float(*)[64])(smem + 19312);    // [8][64]
  __half* xtw = (__half*)(smem + 21360);             // [128][78] halves
  float (*tstT)[12] = (float(*)[12])smem;            // [512][12]
  float (*part)[8][128] = (float(*)[8][128])smem;    // [8][8][128]

  int tid = threadIdx.x;
  int w = tid >> 6, lane = tid & 63;
  // XCD-aware bijective swizzle (gridDim 512 % 8 == 0)
  int bid = blockIdx.x;
  int tile = (bid & 7) * 64 + (bid >> 3);
  size_t rbase = (size_t)tile * 8;
  int n = (int)(rbase >> 9);
  int i0 = (int)(rbase & 511);
  int jlo0 = i0 - 32;

  // ---- Phase A: stage q(+bh), k-window, x-window(fp16); zero avT ----
  if (tid < 64) was[tid] = Wa[tid];
  for (int idx = tid; idx < 71 * 9; idx += 512) ((float*)avT)[idx] = 0.f;
  if (tid < 128) {
    int r = tid >> 4, d4 = (tid & 15) << 2;
    float4 qv = *(const float4*)(q + ((size_t)n * 512 + i0 + r) * 64 + d4);
    float4 bv = *(const float4*)(bh + d4);
    *(float4*)(&qs[r][d4]) =
        make_float4(qv.x + bv.x, qv.y + bv.y, qv.z + bv.z, qv.w + bv.w);
  }
  for (int idx = tid; idx < 71 * 16; idx += 512) {
    int row = idx >> 4, d4 = (idx & 15) << 2;
    int j = jlo0 + row;
    float4 v = make_float4(0.f, 0.f, 0.f, 0.f);
    if (j >= 0 && j < 512)
      v = *(const float4*)(k + ((size_t)n * 512 + j) * 64 + d4);
    *(float4*)(&ks[row][d4]) = v;
  }
  // x-window fp16: 128 c x 18 float4-chunks
  for (int t = tid; t < 128 * 18; t += 512) {
    int c = t / 18;
    int u = t - c * 18;
    int col = 4 * u;
    int j0 = jlo0 + col;
    const float* xp = x + ((size_t)n * 128 + c) * 512;
    float4 v = make_float4(0.f, 0.f, 0.f, 0.f);
    if (j0 >= 0 && j0 + 3 < 512) {
      v = *(const float4*)(xp + j0);
    } else {
      if (j0 + 0 >= 0 && j0 + 0 < 512) v.x = xp[j0 + 0];
      if (j0 + 1 >= 0 && j0 + 1 < 512) v.y = xp[j0 + 1];
      if (j0 + 2 >= 0 && j0 + 2 < 512) v.z = xp[j0 + 2];
      if (j0 + 3 >= 0 && j0 + 3 < 512) v.w = xp[j0 + 3];
    }
    __half2 p01, p23;
    p01.x = __float2half(v.x); p01.y = __float2half(v.y);
    p23.x = __float2half(v.z); p23.y = __float2half(v.w);
    *(__half2*)(xtw + c * 78 + col) = p01;
    *(__half2*)(xtw + c * 78 + col + 2) = p23;
  }
  __syncthreads();

  // ---- Phase A2: scores + softmax + a-write. Wave w -> row w ----
  {
    int r = w;
    int i = i0 + r;
    int j = jlo0 + r + lane;
    bool valid = (j >= 0 && j < 512);
    const float* krow = &ks[r + lane][0];  // stride 68: conflict-free f4
    float e = 0.f;
#pragma unroll
    for (int d4 = 0; d4 < 64; d4 += 4) {
      float4 kv = *(const float4*)(krow + d4);
      float4 qv = *(const float4*)(&qs[r][d4]);
      float4 wv = *(const float4*)(&was[d4]);
      float h0 = qv.x + kv.x, h1 = qv.y + kv.y;
      float h2 = qv.z + kv.z, h3 = qv.w + kv.w;
      float t0 = 1.f - 2.f * __builtin_amdgcn_rcpf(__expf(2.f * h0) + 1.f);
      float t1 = 1.f - 2.f * __builtin_amdgcn_rcpf(__expf(2.f * h1) + 1.f);
      float t2 = 1.f - 2.f * __builtin_amdgcn_rcpf(__expf(2.f * h2) + 1.f);
      float t3 = 1.f - 2.f * __builtin_amdgcn_rcpf(__expf(2.f * h3) + 1.f);
      e += wv.x * t0 + wv.y * t1 + wv.z * t2 + wv.w * t3;
    }
    e += ba[0];
    if (!valid) e = -1e30f;

    float m = e;
    for (int o = 32; o > 0; o >>= 1) m = fmaxf(m, __shfl_xor(m, o, 64));
    float ex = valid ? __expf(e - m) : 0.f;
    float s = ex;
    for (int o = 32; o > 0; o >>= 1) s += __shfl_xor(s, o, 64);
    avT[r + lane][r] = ex / (s + 1e-6f);  // abs col = r + lane

    float* arow = a + ((size_t)n * 512 + i) * 512;
    int jlo = i - 32;
#pragma unroll
    for (int t = 0; t < 2; t++) {
      int col0 = 4 * lane + 256 * t;
      float4 v;
      { int jr = col0 + 0 - jlo; int jc = min(max(jr, 0), 63); v.x = (jr >= 0 && jr < 64) ? avT[r + jc][r] : 0.f; }
      { int jr = col0 + 1 - jlo; int jc = min(max(jr, 0), 63); v.y = (jr >= 0 && jr < 64) ? avT[r + jc][r] : 0.f; }
      { int jr = col0 + 2 - jlo; int jc = min(max(jr, 0), 63); v.z = (jr >= 0 && jr < 64) ? avT[r + jc][r] : 0.f; }
      { int jr = col0 + 3 - jlo; int jc = min(max(jr, 0), 63); v.w = (jr >= 0 && jr < 64) ? avT[r + jc][r] : 0.f; }
      *(float4*)(arow + col0) = v;
    }
  }
  __syncthreads();

  // ---- Phase B: v = a@x + residual(global, exact) -> xstT[c][r] ----
  {
    int c = tid & 127;
    int r0 = (tid >> 7) << 1;  // 0,2,4,6 -> rows r0, r0+1
    const __half* xr = xtw + c * 78;
    const float* xp = x + ((size_t)n * 128 + c) * 512;
    float acc0 = 0.f, acc1 = 0.f;
#pragma unroll 5
    for (int m = 0; m < 65; m++) {
      int col = r0 + m;
      float xv = __half2float(xr[col]);  // u16, 2-way: free
      float a0 = avT[col][r0];           // broadcast
      float a1 = avT[col][r0 + 1];       // broadcast
      acc0 += a0 * xv;
      acc1 += a1 * xv;
    }
    float res0 = xp[i0 + r0];      // L2-hot, exact fp32 residual
    float res1 = xp[i0 + r0 + 1];
    *(float2*)(&xstT[c][r0]) = make_float2(acc0 + res0, acc1 + res1);
  }
  __syncthreads();

  // ---- Phase B2: LN0 in place on xstT. Wave w -> row w ----
  {
    float a0 = xstT[lane][w], a1 = xstT[lane + 64][w];
    float s = a0 + a1, s2 = a0 * a0 + a1 * a1;
    for (int o = 32; o > 0; o >>= 1) {
      s += __shfl_xor(s, o, 64);
      s2 += __shfl_xor(s2, o, 64);
    }
    float mu = s * (1.f / 128.f);
    float var = s2 * (1.f / 128.f) - mu * mu;
    float rs = rsqrtf(var + 1e-5f);
    xstT[lane][w] = (a0 - mu) * rs * g0[lane] + be0[lane];
    xstT[lane + 64][w] = (a1 - mu) * rs * g0[lane + 64] + be0[lane + 64];
  }
  __syncthreads();

  // ---- Phase C: GEMM1 (in-wave 4-way K-split, 4-deep W prefetch) ----
  {
    int g = lane & 15;   // f4-group within wave
    int kq = lane >> 4;  // K-quarter 0..3
    int f0 = (16 * w + g) << 2;
    int ccb = kq << 5;
    const float* w0p = W0 + (size_t)ccb * 512 + f0;
    float acc[8][4];
#pragma unroll
    for (int i = 0; i < 8; i++)
#pragma unroll
      for (int u = 0; u < 4; u++) acc[i][u] = 0.f;

    float4 wbuf[4];
#pragma unroll
    for (int p = 0; p < 4; p++)
      wbuf[p] = *(const float4*)(w0p + (size_t)p * 512);
#pragma unroll
    for (int c4 = 0; c4 < 8; c4++) {
      float4 cur0 = wbuf[0], cur1 = wbuf[1], cur2 = wbuf[2], cur3 = wbuf[3];
      if (c4 < 7) {
#pragma unroll
        for (int p = 0; p < 4; p++)
          wbuf[p] = *(const float4*)(w0p + (size_t)((c4 + 1) * 4 + p) * 512);
      }
#pragma unroll
      for (int p = 0; p < 4; p++) {
        int cc = ccb + c4 * 4 + p;
        float4 wv = (p == 0) ? cur0 : (p == 1) ? cur1 : (p == 2) ? cur2 : cur3;
        float4 xa = *(const float4*)(&xstT[cc][0]);  // broadcast
        float4 xb = *(const float4*)(&xstT[cc][4]);
        acc[0][0] += xa.x * wv.x; acc[0][1] += xa.x * wv.y; acc[0][2] += xa.x * wv.z; acc[0][3] += xa.x * wv.w;
        acc[1][0] += xa.y * wv.x; acc[1][1] += xa.y * wv.y; acc[1][2] += xa.y * wv.z; acc[1][3] += xa.y * wv.w;
        acc[2][0] += xa.z * wv.x; acc[2][1] += xa.z * wv.y; acc[2][2] += xa.z * wv.z; acc[2][3] += xa.z * wv.w;
        acc[3][0] += xa.w * wv.x; acc[3][1] += xa.w * wv.y; acc[3][2] += xa.w * wv.z; acc[3][3] += xa.w * wv.w;
        acc[4][0] += xb.x * wv.x; acc[4][1] += xb.x * wv.y; acc[4][2] += xb.x * wv.z; acc[4][3] += xb.x * wv.w;
        acc[5][0] += xb.y * wv.x; acc[5][1] += xb.y * wv.y; acc[5][2] += xb.y * wv.z; acc[5][3] += xb.y * wv.w;
        acc[6][0] += xb.z * wv.x; acc[6][1] += xb.z * wv.y; acc[6][2] += xb.z * wv.z; acc[6][3] += xb.z * wv.w;
        acc[7][0] += xb.w * wv.x; acc[7][1] += xb.w * wv.y; acc[7][2] += xb.w * wv.z; acc[7][3] += xb.w * wv.w;
      }
    }
    // butterfly-reduce over kq (lane bits 4,5)
#pragma unroll
    for (int i = 0; i < 8; i++)
#pragma unroll
      for (int u = 0; u < 4; u++) {
        float v = acc[i][u];
        v += __shfl_xor(v, 16, 64);
        v += __shfl_xor(v, 32, 64);
        acc[i][u] = v;
      }
    int f = f0 + kq;
    float bb = b0[f];
    float r0v[8];
#pragma unroll
    for (int i = 0; i < 8; i++) {
      float v = (kq == 0) ? acc[i][0] : (kq == 1) ? acc[i][1]
              : (kq == 2) ? acc[i][2] : acc[i][3];
      r0v[i] = fmaxf(v + bb, 0.f);
    }
    *(float4*)(&tstT[f][0]) = make_float4(r0v[0], r0v[1], r0v[2], r0v[3]);
    *(float4*)(&tstT[f][4]) = make_float4(r0v[4], r0v[5], r0v[6], r0v[7]);
  }
  __syncthreads();

  // ---- Phase C2: GEMM2 (wave = K-octile, 4-deep W prefetch), acc in regs ----
  float g2acc[4][4];
  {
    int c0 = (lane & 31) << 2;
    int rh = lane >> 5;  // 0..1 -> rows 4rh..4rh+3
    const float* W1p = W1 + (size_t)w * 64 * 128 + c0;
    int tb = w << 6;
#pragma unroll
    for (int i = 0; i < 4; i++)
#pragma unroll
      for (int u = 0; u < 4; u++) g2acc[i][u] = 0.f;

    float4 wbuf[4];
#pragma unroll
    for (int p = 0; p < 4; p++)
      wbuf[p] = *(const float4*)(W1p + (size_t)p * 128);
#pragma unroll
    for (int t4 = 0; t4 < 16; t4++) {
      float4 cur0 = wbuf[0], cur1 = wbuf[1], cur2 = wbuf[2], cur3 = wbuf[3];
      if (t4 < 15) {
#pragma unroll
        for (int p = 0; p < 4; p++)
          wbuf[p] = *(const float4*)(W1p + (size_t)((t4 + 1) * 4 + p) * 128);
      }
#pragma unroll
      for (int p = 0; p < 4; p++) {
        int t = t4 * 4 + p;
        float4 wv = (p == 0) ? cur0 : (p == 1) ? cur1 : (p == 2) ? cur2 : cur3;
        float4 tv = *(const float4*)(&tstT[tb + t][4 * rh]);  // 2-addr bcast
        g2acc[0][0] += tv.x * wv.x; g2acc[0][1] += tv.x * wv.y; g2acc[0][2] += tv.x * wv.z; g2acc[0][3] += tv.x * wv.w;
        g2acc[1][0] += tv.y * wv.x; g2acc[1][1] += tv.y * wv.y; g2acc[1][2] += tv.y * wv.z; g2acc[1][3] += tv.y * wv.w;
        g2acc[2][0] += tv.z * wv.x; g2acc[2][1] += tv.z * wv.y; g2acc[2][2] += tv.z * wv.z; g2acc[2][3] += tv.z * wv.w;
        g2acc[3][0] += tv.w * wv.x; g2acc[3][1] += tv.w * wv.y; g2acc[3][2] += tv.w * wv.z; g2acc[3][3] += tv.w * wv.w;
      }
    }
  }
  __syncthreads();  // tstT reads done by ALL waves -> part may overwrite

  {
    int c0 = (lane & 31) << 2;
    int rh = lane >> 5;
#pragma unroll
    for (int i = 0; i < 4; i++) {
      *(float4*)(&part[w][4 * rh + i][c0]) =
          make_float4(g2acc[i][0], g2acc[i][1], g2acc[i][2], g2acc[i][3]);
    }
  }
  __syncthreads();

  // ---- merged combine + bias + residual + LN1 -> back into xstT ----
  {
    float a0 = b1[lane] + xstT[lane][w];
    float a1 = b1[lane + 64] + xstT[lane + 64][w];
#pragma unroll
    for (int ko = 0; ko < 8; ko++) {
      a0 += part[ko][w][lane];        // conflict-free b32
      a1 += part[ko][w][lane + 64];
    }
    float s = a0 + a1, s2 = a0 * a0 + a1 * a1;
    for (int o = 32; o > 0; o >>= 1) {
      s += __shfl_xor(s, o, 64);
      s2 += __shfl_xor(s2, o, 64);
    }
    float mu = s * (1.f / 128.f);
    float var = s2 * (1.f / 128.f) - mu * mu;
    float rs = rsqrtf(var + 1e-5f);
    xstT[lane][w] = (a0 - mu) * rs * g1[lane] + be1[lane];       // RMW own slot
    xstT[lane + 64][w] = (a1 - mu) * rs * g1[lane + 64] + be1[lane + 64];
  }
  __syncthreads();

  // ---- transposed write: out (N,C,L); 8 consecutive l per c ----
  {
    int c = tid >> 2, tq = tid & 3;
    *(float2*)(out + ((size_t)n * 128 + c) * 512 + i0 + 2 * tq) =
        make_float2(xstT[c][2 * tq], xstT[c][2 * tq + 1]);
  }
}

// ---------------------------------------------------------------------------
extern "C" void kernel_launch(void* const* d_in, const int* in_sizes, int n_in,
                              void* d_out, int out_size, void* d_ws, size_t ws_size,
                              hipStream_t stream) {
  const float* x   = (const float*)d_in[0];
  const float* Wx  = (const float*)d_in[1];
  const float* Wt  = (const float*)d_in[2];
  const float* bh  = (const float*)d_in[3];
  const float* Wa  = (const float*)d_in[4];
  const float* ba  = (const float*)d_in[5];
  const float* W0  = (const float*)d_in[6];
  const float* b0  = (const float*)d_in[7];
  const float* W1  = (const float*)d_in[8];
  const float* b1  = (const float*)d_in[9];
  const float* g0  = (const float*)d_in[10];
  const float* be0 = (const float*)d_in[11];
  const float* g1  = (const float*)d_in[12];
  const float* be1 = (const float*)d_in[13];

  float* outx = (float*)d_out;           // N*C*L = 524288
  float* outa = outx + (size_t)524288;   // N*L*L = 2097152

  float* ws = (float*)d_ws;
  float* q  = ws;              // 262144
  float* k  = q + 262144;      // 262144

  prep_kernel<<<256, 512, 0, stream>>>(x, Wt, Wx, q, k);
  attn_ffn_fused_kernel<<<512, 512, 0, stream>>>(
      x, q, k, bh, Wa, ba, g0, be0, W0, b0, W1, b1, g1, be1, outa, outx);
}

// Round 8
// 122.117 us; speedup vs baseline: 1.0895x; 1.0482x over previous
//
#include <hip/hip_runtime.h>
#include <hip/hip_fp16.h>
#include <cstddef>

// N=8, C=128, L=512, D=64, F=512, ATTN_W=64

// ---------------------------------------------------------------------------
// Kernel 1: prep = q/k projection only. grid 256, block 512.
// Block = (n, l-tile of 16). Half 0 (tid<256): q via Wt; half 1: k via Wx.
// ---------------------------------------------------------------------------
__global__ __launch_bounds__(512) void prep_kernel(
    const float* __restrict__ x, const float* __restrict__ Wt,
    const float* __restrict__ Wx, float* __restrict__ q,
    float* __restrict__ k) {
  __shared__ float xs[128][17];
  int tid = threadIdx.x;
  int n = blockIdx.x >> 5;
  int l0 = (blockIdx.x & 31) << 4;

  {  // stage x tile: 128 c x 16 l  (512 float4 tasks, one per thread)
    int c = tid >> 2, v = tid & 3;
    float4 d4 = *(const float4*)(x + ((size_t)n * 128 + c) * 512 + l0 + 4 * v);
    xs[c][4 * v + 0] = d4.x; xs[c][4 * v + 1] = d4.y;
    xs[c][4 * v + 2] = d4.z; xs[c][4 * v + 3] = d4.w;
  }
  __syncthreads();

  int half = tid >> 8;       // 0: q/Wt, 1: k/Wx
  int t = tid & 255;
  int r = t >> 4;            // 0..15
  int f0 = (t & 15) << 2;    // 0..60
  const float* W = half ? Wx : Wt;
  float* dst = half ? k : q;
  float acc[4] = {0.f, 0.f, 0.f, 0.f};
#pragma unroll 4
  for (int cc = 0; cc < 128; cc++) {
    float xv = xs[cc][r];
    float4 w = *(const float4*)(W + cc * 64 + f0);
    acc[0] += xv * w.x; acc[1] += xv * w.y;
    acc[2] += xv * w.z; acc[3] += xv * w.w;
  }
  *(float4*)(dst + ((size_t)n * 512 + l0 + r) * 64 + f0) =
      make_float4(acc[0], acc[1], acc[2], acc[3]);
}

// ---------------------------------------------------------------------------
// Kernel 2: FUSED attn+FFN. 8 rows/block, grid 512, block 512 (8 waves).
// R8: phase-B LDS issues cut 195 -> ~63/thread. Thread (c,g) computes the
// band-matmul partial for cols 18g..18g+17 over ALL 8 rows (x read once as
// half2 per 2 cols, av as 4 b128 broadcasts), partials into partB (dead ks
// region), then a combine pass adds 4 partials + exact fp32 residual.
// ---------------------------------------------------------------------------
__global__ __launch_bounds__(512, 4) void attn_ffn_fused_kernel(
    const float* __restrict__ x, const float* __restrict__ q,
    const float* __restrict__ k, const float* __restrict__ bh,
    const float* __restrict__ Wa, const float* __restrict__ ba,
    const float* __restrict__ g0, const float* __restrict__ be0,
    const float* __restrict__ W0, const float* __restrict__ b0,
    const float* __restrict__ W1, const float* __restrict__ b1,
    const float* __restrict__ g1, const float* __restrict__ be1,
    float* __restrict__ a, float* __restrict__ out) {
  // Aliased region (41328 B), timeline:
  //  A/A2:  ks[71][68] @0 (19312), qs[8][64] @19312 (2048), xtw @21360 (19968)
  //  B1:    partB[4][8][128] @0 (16384)  [ks/qs dead; xtw still live]
  //  C:     tstT[512][12] @0 (24576)     [partB dead]
  //  C2+:   part[8][8][128] @0 (32768)   [tstT dead]
  __shared__ __align__(16) char smem[41328];
  __shared__ __align__(16) float xstT[128][12];  // x2 tile [c][r]
  __shared__ __align__(16) float avT[72][12];    // [abs_col][row], b128 rows
  __shared__ float was[64];

  float (*ks)[68] = (float(*)[68])smem;              // [71][68]
  float (*qs)[64] = (float(*)[64])(smem + 19312);    // [8][64]
  __half* xtw = (__half*)(smem + 21360);             // [128][78] halves
  float (*partB)[8][128] = (float(*)[8][128])smem;   // [4][8][128]
  float (*tstT)[12] = (float(*)[12])smem;            // [512][12]
  float (*part)[8][128] = (float(*)[8][128])smem;    // [8][8][128]

  int tid = threadIdx.x;
  int w = tid >> 6, lane = tid & 63;
  // XCD-aware bijective swizzle (gridDim 512 % 8 == 0)
  int bid = blockIdx.x;
  int tile = (bid & 7) * 64 + (bid >> 3);
  size_t rbase = (size_t)tile * 8;
  int n = (int)(rbase >> 9);
  int i0 = (int)(rbase & 511);
  int jlo0 = i0 - 32;

  // ---- Phase A: stage q(+bh), k-window, x-window(fp16); zero avT ----
  if (tid < 64) was[tid] = Wa[tid];
  for (int idx = tid; idx < 72 * 12; idx += 512) ((float*)avT)[idx] = 0.f;
  if (tid < 128) {
    int r = tid >> 4, d4 = (tid & 15) << 2;
    float4 qv = *(const float4*)(q + ((size_t)n * 512 + i0 + r) * 64 + d4);
    float4 bv = *(const float4*)(bh + d4);
    *(float4*)(&qs[r][d4]) =
        make_float4(qv.x + bv.x, qv.y + bv.y, qv.z + bv.z, qv.w + bv.w);
  }
  for (int idx = tid; idx < 71 * 16; idx += 512) {
    int row = idx >> 4, d4 = (idx & 15) << 2;
    int j = jlo0 + row;
    float4 v = make_float4(0.f, 0.f, 0.f, 0.f);
    if (j >= 0 && j < 512)
      v = *(const float4*)(k + ((size_t)n * 512 + j) * 64 + d4);
    *(float4*)(&ks[row][d4]) = v;
  }
  // x-window fp16: 128 c x 18 float4-chunks (cols 0..71, OOB = 0)
  for (int t = tid; t < 128 * 18; t += 512) {
    int c = t / 18;
    int u = t - c * 18;
    int col = 4 * u;
    int j0 = jlo0 + col;
    const float* xp = x + ((size_t)n * 128 + c) * 512;
    float4 v = make_float4(0.f, 0.f, 0.f, 0.f);
    if (j0 >= 0 && j0 + 3 < 512) {
      v = *(const float4*)(xp + j0);
    } else {
      if (j0 + 0 >= 0 && j0 + 0 < 512) v.x = xp[j0 + 0];
      if (j0 + 1 >= 0 && j0 + 1 < 512) v.y = xp[j0 + 1];
      if (j0 + 2 >= 0 && j0 + 2 < 512) v.z = xp[j0 + 2];
      if (j0 + 3 >= 0 && j0 + 3 < 512) v.w = xp[j0 + 3];
    }
    __half2 p01, p23;
    p01.x = __float2half(v.x); p01.y = __float2half(v.y);
    p23.x = __float2half(v.z); p23.y = __float2half(v.w);
    *(__half2*)(xtw + c * 78 + col) = p01;
    *(__half2*)(xtw + c * 78 + col + 2) = p23;
  }
  __syncthreads();

  // ---- Phase A2: scores + softmax + a-write. Wave w -> row w ----
  {
    int r = w;
    int i = i0 + r;
    int j = jlo0 + r + lane;
    bool valid = (j >= 0 && j < 512);
    const float* krow = &ks[r + lane][0];  // stride 68
    float e = 0.f;
#pragma unroll
    for (int d4 = 0; d4 < 64; d4 += 4) {
      float4 kv = *(const float4*)(krow + d4);
      float4 qv = *(const float4*)(&qs[r][d4]);
      float4 wv = *(const float4*)(&was[d4]);
      float h0 = qv.x + kv.x, h1 = qv.y + kv.y;
      float h2 = qv.z + kv.z, h3 = qv.w + kv.w;
      float t0 = 1.f - 2.f * __builtin_amdgcn_rcpf(__expf(2.f * h0) + 1.f);
      float t1 = 1.f - 2.f * __builtin_amdgcn_rcpf(__expf(2.f * h1) + 1.f);
      float t2 = 1.f - 2.f * __builtin_amdgcn_rcpf(__expf(2.f * h2) + 1.f);
      float t3 = 1.f - 2.f * __builtin_amdgcn_rcpf(__expf(2.f * h3) + 1.f);
      e += wv.x * t0 + wv.y * t1 + wv.z * t2 + wv.w * t3;
    }
    e += ba[0];
    if (!valid) e = -1e30f;

    float m = e;
    for (int o = 32; o > 0; o >>= 1) m = fmaxf(m, __shfl_xor(m, o, 64));
    float ex = valid ? __expf(e - m) : 0.f;
    float s = ex;
    for (int o = 32; o > 0; o >>= 1) s += __shfl_xor(s, o, 64);
    avT[r + lane][r] = ex / (s + 1e-6f);  // abs col = r + lane

    float* arow = a + ((size_t)n * 512 + i) * 512;
    int jlo = i - 32;
#pragma unroll
    for (int t = 0; t < 2; t++) {
      int col0 = 4 * lane + 256 * t;
      float4 v;
      { int jr = col0 + 0 - jlo; int jc = min(max(jr, 0), 63); v.x = (jr >= 0 && jr < 64) ? avT[r + jc][r] : 0.f; }
      { int jr = col0 + 1 - jlo; int jc = min(max(jr, 0), 63); v.y = (jr >= 0 && jr < 64) ? avT[r + jc][r] : 0.f; }
      { int jr = col0 + 2 - jlo; int jc = min(max(jr, 0), 63); v.z = (jr >= 0 && jr < 64) ? avT[r + jc][r] : 0.f; }
      { int jr = col0 + 3 - jlo; int jc = min(max(jr, 0), 63); v.w = (jr >= 0 && jr < 64) ? avT[r + jc][r] : 0.f; }
      *(float4*)(arow + col0) = v;
    }
  }
  __syncthreads();

  // ---- Phase B1: band-matmul partials. Thread (c,g): cols 18g..18g+17,
  //      ALL 8 rows. 5 LDS issues per 2 cols. partB over dead ks/qs. ----
  {
    int c = tid & 127;
    int g = tid >> 7;  // 0..3
    const __half* xr = xtw + c * 78;
    float acc[8] = {0.f, 0.f, 0.f, 0.f, 0.f, 0.f, 0.f, 0.f};
    int colb = 18 * g;
#pragma unroll
    for (int u = 0; u < 9; u++) {
      int col = colb + 2 * u;
      __half2 xh = *(const __half2*)(xr + col);
      float xv0 = __half2float(__low2half(xh));
      float xv1 = __half2float(__high2half(xh));
      float4 a0lo = *(const float4*)(&avT[col][0]);      // broadcast b128
      float4 a0hi = *(const float4*)(&avT[col][4]);
      float4 a1lo = *(const float4*)(&avT[col + 1][0]);
      float4 a1hi = *(const float4*)(&avT[col + 1][4]);
      acc[0] += a0lo.x * xv0 + a1lo.x * xv1;
      acc[1] += a0lo.y * xv0 + a1lo.y * xv1;
      acc[2] += a0lo.z * xv0 + a1lo.z * xv1;
      acc[3] += a0lo.w * xv0 + a1lo.w * xv1;
      acc[4] += a0hi.x * xv0 + a1hi.x * xv1;
      acc[5] += a0hi.y * xv0 + a1hi.y * xv1;
      acc[6] += a0hi.z * xv0 + a1hi.z * xv1;
      acc[7] += a0hi.w * xv0 + a1hi.w * xv1;
    }
#pragma unroll
    for (int r = 0; r < 8; r++) partB[g][r][c] = acc[r];  // lane-consecutive
  }
  __syncthreads();

  // ---- Phase B-combine: sum partials + exact fp32 residual -> xstT ----
  {
    int c = tid & 127;
    int r = tid >> 7;  // rows r and r+4
    const float* xp = x + ((size_t)n * 128 + c) * 512;
    float s0 = partB[0][r][c] + partB[1][r][c] + partB[2][r][c] + partB[3][r][c];
    float s1 = partB[0][r + 4][c] + partB[1][r + 4][c] +
               partB[2][r + 4][c] + partB[3][r + 4][c];
    xstT[c][r] = s0 + xp[i0 + r];
    xstT[c][r + 4] = s1 + xp[i0 + r + 4];
  }
  __syncthreads();

  // ---- Phase B2: LN0 in place on xstT. Wave w -> row w ----
  {
    float a0 = xstT[lane][w], a1 = xstT[lane + 64][w];
    float s = a0 + a1, s2 = a0 * a0 + a1 * a1;
    for (int o = 32; o > 0; o >>= 1) {
      s += __shfl_xor(s, o, 64);
      s2 += __shfl_xor(s2, o, 64);
    }
    float mu = s * (1.f / 128.f);
    float var = s2 * (1.f / 128.f) - mu * mu;
    float rs = rsqrtf(var + 1e-5f);
    xstT[lane][w] = (a0 - mu) * rs * g0[lane] + be0[lane];
    xstT[lane + 64][w] = (a1 - mu) * rs * g0[lane + 64] + be0[lane + 64];
  }
  __syncthreads();

  // ---- Phase C: GEMM1 (in-wave 4-way K-split, 4-deep W prefetch) ----
  {
    int g = lane & 15;   // f4-group within wave
    int kq = lane >> 4;  // K-quarter 0..3
    int f0 = (16 * w + g) << 2;
    int ccb = kq << 5;
    const float* w0p = W0 + (size_t)ccb * 512 + f0;
    float acc[8][4];
#pragma unroll
    for (int i = 0; i < 8; i++)
#pragma unroll
      for (int u = 0; u < 4; u++) acc[i][u] = 0.f;

    float4 wbuf[4];
#pragma unroll
    for (int p = 0; p < 4; p++)
      wbuf[p] = *(const float4*)(w0p + (size_t)p * 512);
#pragma unroll
    for (int c4 = 0; c4 < 8; c4++) {
      float4 cur0 = wbuf[0], cur1 = wbuf[1], cur2 = wbuf[2], cur3 = wbuf[3];
      if (c4 < 7) {
#pragma unroll
        for (int p = 0; p < 4; p++)
          wbuf[p] = *(const float4*)(w0p + (size_t)((c4 + 1) * 4 + p) * 512);
      }
#pragma unroll
      for (int p = 0; p < 4; p++) {
        int cc = ccb + c4 * 4 + p;
        float4 wv = (p == 0) ? cur0 : (p == 1) ? cur1 : (p == 2) ? cur2 : cur3;
        float4 xa = *(const float4*)(&xstT[cc][0]);  // broadcast
        float4 xb = *(const float4*)(&xstT[cc][4]);
        acc[0][0] += xa.x * wv.x; acc[0][1] += xa.x * wv.y; acc[0][2] += xa.x * wv.z; acc[0][3] += xa.x * wv.w;
        acc[1][0] += xa.y * wv.x; acc[1][1] += xa.y * wv.y; acc[1][2] += xa.y * wv.z; acc[1][3] += xa.y * wv.w;
        acc[2][0] += xa.z * wv.x; acc[2][1] += xa.z * wv.y; acc[2][2] += xa.z * wv.z; acc[2][3] += xa.z * wv.w;
        acc[3][0] += xa.w * wv.x; acc[3][1] += xa.w * wv.y; acc[3][2] += xa.w * wv.z; acc[3][3] += xa.w * wv.w;
        acc[4][0] += xb.x * wv.x; acc[4][1] += xb.x * wv.y; acc[4][2] += xb.x * wv.z; acc[4][3] += xb.x * wv.w;
        acc[5][0] += xb.y * wv.x; acc[5][1] += xb.y * wv.y; acc[5][2] += xb.y * wv.z; acc[5][3] += xb.y * wv.w;
        acc[6][0] += xb.z * wv.x; acc[6][1] += xb.z * wv.y; acc[6][2] += xb.z * wv.z; acc[6][3] += xb.z * wv.w;
        acc[7][0] += xb.w * wv.x; acc[7][1] += xb.w * wv.y; acc[7][2] += xb.w * wv.z; acc[7][3] += xb.w * wv.w;
      }
    }
    // butterfly-reduce over kq (lane bits 4,5)
#pragma unroll
    for (int i = 0; i < 8; i++)
#pragma unroll
      for (int u = 0; u < 4; u++) {
        float v = acc[i][u];
        v += __shfl_xor(v, 16, 64);
        v += __shfl_xor(v, 32, 64);
        acc[i][u] = v;
      }
    int f = f0 + kq;
    float bb = b0[f];
    float r0v[8];
#pragma unroll
    for (int i = 0; i < 8; i++) {
      float v = (kq == 0) ? acc[i][0] : (kq == 1) ? acc[i][1]
              : (kq == 2) ? acc[i][2] : acc[i][3];
      r0v[i] = fmaxf(v + bb, 0.f);
    }
    *(float4*)(&tstT[f][0]) = make_float4(r0v[0], r0v[1], r0v[2], r0v[3]);
    *(float4*)(&tstT[f][4]) = make_float4(r0v[4], r0v[5], r0v[6], r0v[7]);
  }
  __syncthreads();

  // ---- Phase C2: GEMM2 (wave = K-octile, 4-deep W prefetch), acc in regs ----
  float g2acc[4][4];
  {
    int c0 = (lane & 31) << 2;
    int rh = lane >> 5;  // 0..1 -> rows 4rh..4rh+3
    const float* W1p = W1 + (size_t)w * 64 * 128 + c0;
    int tb = w << 6;
#pragma unroll
    for (int i = 0; i < 4; i++)
#pragma unroll
      for (int u = 0; u < 4; u++) g2acc[i][u] = 0.f;

    float4 wbuf[4];
#pragma unroll
    for (int p = 0; p < 4; p++)
      wbuf[p] = *(const float4*)(W1p + (size_t)p * 128);
#pragma unroll
    for (int t4 = 0; t4 < 16; t4++) {
      float4 cur0 = wbuf[0], cur1 = wbuf[1], cur2 = wbuf[2], cur3 = wbuf[3];
      if (t4 < 15) {
#pragma unroll
        for (int p = 0; p < 4; p++)
          wbuf[p] = *(const float4*)(W1p + (size_t)((t4 + 1) * 4 + p) * 128);
      }
#pragma unroll
      for (int p = 0; p < 4; p++) {
        int t = t4 * 4 + p;
        float4 wv = (p == 0) ? cur0 : (p == 1) ? cur1 : (p == 2) ? cur2 : cur3;
        float4 tv = *(const float4*)(&tstT[tb + t][4 * rh]);  // 2-addr bcast
        g2acc[0][0] += tv.x * wv.x; g2acc[0][1] += tv.x * wv.y; g2acc[0][2] += tv.x * wv.z; g2acc[0][3] += tv.x * wv.w;
        g2acc[1][0] += tv.y * wv.x; g2acc[1][1] += tv.y * wv.y; g2acc[1][2] += tv.y * wv.z; g2acc[1][3] += tv.y * wv.w;
        g2acc[2][0] += tv.z * wv.x; g2acc[2][1] += tv.z * wv.y; g2acc[2][2] += tv.z * wv.z; g2acc[2][3] += tv.z * wv.w;
        g2acc[3][0] += tv.w * wv.x; g2acc[3][1] += tv.w * wv.y; g2acc[3][2] += tv.w * wv.z; g2acc[3][3] += tv.w * wv.w;
      }
    }
  }
  __syncthreads();  // tstT reads done by ALL waves -> part may overwrite

  {
    int c0 = (lane & 31) << 2;
    int rh = lane >> 5;
#pragma unroll
    for (int i = 0; i < 4; i++) {
      *(float4*)(&part[w][4 * rh + i][c0]) =
          make_float4(g2acc[i][0], g2acc[i][1], g2acc[i][2], g2acc[i][3]);
    }
  }
  __syncthreads();

  // ---- merged combine + bias + residual + LN1 -> back into xstT ----
  {
    float a0 = b1[lane] + xstT[lane][w];
    float a1 = b1[lane + 64] + xstT[lane + 64][w];
#pragma unroll
    for (int ko = 0; ko < 8; ko++) {
      a0 += part[ko][w][lane];        // conflict-free b32
      a1 += part[ko][w][lane + 64];
    }
    float s = a0 + a1, s2 = a0 * a0 + a1 * a1;
    for (int o = 32; o > 0; o >>= 1) {
      s += __shfl_xor(s, o, 64);
      s2 += __shfl_xor(s2, o, 64);
    }
    float mu = s * (1.f / 128.f);
    float var = s2 * (1.f / 128.f) - mu * mu;
    float rs = rsqrtf(var + 1e-5f);
    xstT[lane][w] = (a0 - mu) * rs * g1[lane] + be1[lane];       // RMW own slot
    xstT[lane + 64][w] = (a1 - mu) * rs * g1[lane + 64] + be1[lane + 64];
  }
  __syncthreads();

  // ---- transposed write: out (N,C,L); 8 consecutive l per c ----
  {
    int c = tid >> 2, tq = tid & 3;
    *(float2*)(out + ((size_t)n * 128 + c) * 512 + i0 + 2 * tq) =
        make_float2(xstT[c][2 * tq], xstT[c][2 * tq + 1]);
  }
}

// ---------------------------------------------------------------------------
extern "C" void kernel_launch(void* const* d_in, const int* in_sizes, int n_in,
                              void* d_out, int out_size, void* d_ws, size_t ws_size,
                              hipStream_t stream) {
  const float* x   = (const float*)d_in[0];
  const float* Wx  = (const float*)d_in[1];
  const float* Wt  = (const float*)d_in[2];
  const float* bh  = (const float*)d_in[3];
  const float* Wa  = (const float*)d_in[4];
  const float* ba  = (const float*)d_in[5];
  const float* W0  = (const float*)d_in[6];
  const float* b0  = (const float*)d_in[7];
  const float* W1  = (const float*)d_in[8];
  const float* b1  = (const float*)d_in[9];
  const float* g0  = (const float*)d_in[10];
  const float* be0 = (const float*)d_in[11];
  const float* g1  = (const float*)d_in[12];
  const float* be1 = (const float*)d_in[13];

  float* outx = (float*)d_out;           // N*C*L = 524288
  float* outa = outx + (size_t)524288;   // N*L*L = 2097152

  float* ws = (float*)d_ws;
  float* q  = ws;              // 262144
  float* k  = q + 262144;      // 262144

  prep_kernel<<<256, 512, 0, stream>>>(x, Wt, Wx, q, k);
  attn_ffn_fused_kernel<<<512, 512, 0, stream>>>(
      x, q, k, bh, Wa, ba, g0, be0, W0, b0, W1, b1, g1, be1, outa, outx);
}

// Round 10
// 110.299 us; speedup vs baseline: 1.2062x; 1.1071x over previous
//
#include <hip/hip_runtime.h>
#include <hip/hip_fp16.h>
#include <cstddef>

// N=8, C=128, L=512, D=64, F=512, ATTN_W=64

typedef _Float16 half8_t __attribute__((ext_vector_type(8)));
typedef float f32x4_t __attribute__((ext_vector_type(4)));

// ---------------------------------------------------------------------------
// Kernel 1: prep = q/k projection + W0/W1 fp16 MFMA-fragment pre-pack.
// grid 256, block 512. Block = (n, l-tile of 16).
// Pack: block b < 128 -> W0p tile b (ft=b>>2, ks=b&3); else W1p tile b-128.
// Fragment layout (v_mfma_f32_16x16x32_f16 B): lane l holds
// B[k = ks*32 + (l>>4)*8 + j][col = ft*16 + (l&15)], j=0..7, 16B contiguous.
// ---------------------------------------------------------------------------
__global__ __launch_bounds__(512) void prep_kernel(
    const float* __restrict__ x, const float* __restrict__ Wt,
    const float* __restrict__ Wx, const float* __restrict__ W0,
    const float* __restrict__ W1, float* __restrict__ q,
    float* __restrict__ k, _Float16* __restrict__ W0p,
    _Float16* __restrict__ W1p) {
  __shared__ float xs[128][17];
  int tid = threadIdx.x;
  int n = blockIdx.x >> 5;
  int l0 = (blockIdx.x & 31) << 4;

  {  // stage x tile: 128 c x 16 l
    int c = tid >> 2, v = tid & 3;
    float4 d4 = *(const float4*)(x + ((size_t)n * 128 + c) * 512 + l0 + 4 * v);
    xs[c][4 * v + 0] = d4.x; xs[c][4 * v + 1] = d4.y;
    xs[c][4 * v + 2] = d4.z; xs[c][4 * v + 3] = d4.w;
  }
  __syncthreads();

  int half = tid >> 8;       // 0: q/Wt, 1: k/Wx
  int t = tid & 255;
  int r = t >> 4;            // 0..15
  int f0 = (t & 15) << 2;    // 0..60
  const float* W = half ? Wx : Wt;
  float* dst = half ? k : q;
  float acc[4] = {0.f, 0.f, 0.f, 0.f};
#pragma unroll 4
  for (int cc = 0; cc < 128; cc++) {
    float xv = xs[cc][r];
    float4 w = *(const float4*)(W + cc * 64 + f0);
    acc[0] += xv * w.x; acc[1] += xv * w.y;
    acc[2] += xv * w.z; acc[3] += xv * w.w;
  }
  *(float4*)(dst + ((size_t)n * 512 + l0 + r) * 64 + f0) =
      make_float4(acc[0], acc[1], acc[2], acc[3]);

  // ---- weight pre-pack (one fragment-tile per block, lanes 0..63) ----
  if (tid < 64) {
    int b = blockIdx.x;
    int l15 = tid & 15, lk = tid >> 4;
    if (b < 128) {           // W0p: ft 0..31, ks 0..3
      int ft = b >> 2, ks = b & 3;
      const float* src = W0 + (size_t)(ks * 32 + lk * 8) * 512 + ft * 16 + l15;
      half8_t v;
#pragma unroll
      for (int j = 0; j < 8; j++) v[j] = (_Float16)src[(size_t)j * 512];
      *(half8_t*)(W0p + (size_t)b * 512 + tid * 8) = v;
    } else {                 // W1p: ft 0..7, ks 0..15
      int tt = b - 128;
      int ft = tt >> 4, ks = tt & 15;
      const float* src = W1 + (size_t)(ks * 32 + lk * 8) * 128 + ft * 16 + l15;
      half8_t v;
#pragma unroll
      for (int j = 0; j < 8; j++) v[j] = (_Float16)src[(size_t)j * 128];
      *(half8_t*)(W1p + (size_t)tt * 512 + tid * 8) = v;
    }
  }
}

// ---------------------------------------------------------------------------
// Kernel 2: FUSED attn+FFN. 8 rows/block, grid 512, block 512 (8 waves).
// R9/R10: FFN GEMMs on MFMA (mfma_f32_16x16x32_f16, fp32 accumulate).
// M=16 (rows 8-15 zero-padded), A staged fp16 in LDS, B pre-packed fragments
// streamed from L2 (W0p/W1p, 256 KB total). Kills 2048 VALU FMA/thread, the
// shfl butterfly (64 ds_swizzle), and the part[] partial round-trip.
// ---------------------------------------------------------------------------
__global__ __launch_bounds__(512, 4) void attn_ffn_fused_kernel(
    const float* __restrict__ x, const float* __restrict__ q,
    const float* __restrict__ k, const float* __restrict__ bh,
    const float* __restrict__ Wa, const float* __restrict__ ba,
    const float* __restrict__ g0, const float* __restrict__ be0,
    const _Float16* __restrict__ W0p, const float* __restrict__ b0,
    const _Float16* __restrict__ W1p, const float* __restrict__ b1,
    const float* __restrict__ g1, const float* __restrict__ be1,
    float* __restrict__ a, float* __restrict__ out) {
  // Aliased region (41328 B), timeline:
  //  A/A2:  ks[71][68] @0 (19312), qs[8][64] @19312 (2048), xtw @21360 (19968)
  //  B1:    partB[4][8][128] @0 (16384)  [ks/qs dead; xtw still live]
  //  FFN:   x2h f16[16][136] @0 (4352), tsth f16[16][520] @4352 (16640),
  //         ys f32[8][128] @20992 (4096)
  __shared__ __align__(16) char smem[41328];
  __shared__ __align__(16) float xstT[128][12];  // x2 tile [c][r]
  __shared__ __align__(16) float avT[72][12];    // [abs_col][row], b128 rows
  __shared__ float was[64];

  float (*ks)[68] = (float(*)[68])smem;              // [71][68]
  float (*qs)[64] = (float(*)[64])(smem + 19312);    // [8][64]
  __half* xtw = (__half*)(smem + 21360);             // [128][78] halves
  float (*partB)[8][128] = (float(*)[8][128])smem;   // [4][8][128]
  _Float16* x2h = (_Float16*)smem;                   // [16][136]
  _Float16* tsth = (_Float16*)(smem + 4352);         // [16][520]
  float (*ys)[128] = (float(*)[128])(smem + 20992);  // [8][128]

  int tid = threadIdx.x;
  int w = tid >> 6, lane = tid & 63;
  // XCD-aware bijective swizzle (gridDim 512 % 8 == 0)
  int bid = blockIdx.x;
  int tile = (bid & 7) * 64 + (bid >> 3);
  size_t rbase = (size_t)tile * 8;
  int n = (int)(rbase >> 9);
  int i0 = (int)(rbase & 511);
  int jlo0 = i0 - 32;

  // ---- Phase A: stage q(+bh), k-window, x-window(fp16); zero avT ----
  if (tid < 64) was[tid] = Wa[tid];
  for (int idx = tid; idx < 72 * 12; idx += 512) ((float*)avT)[idx] = 0.f;
  if (tid < 128) {
    int r = tid >> 4, d4 = (tid & 15) << 2;
    float4 qv = *(const float4*)(q + ((size_t)n * 512 + i0 + r) * 64 + d4);
    float4 bv = *(const float4*)(bh + d4);
    *(float4*)(&qs[r][d4]) =
        make_float4(qv.x + bv.x, qv.y + bv.y, qv.z + bv.z, qv.w + bv.w);
  }
  for (int idx = tid; idx < 71 * 16; idx += 512) {
    int row = idx >> 4, d4 = (idx & 15) << 2;
    int j = jlo0 + row;
    float4 v = make_float4(0.f, 0.f, 0.f, 0.f);
    if (j >= 0 && j < 512)
      v = *(const float4*)(k + ((size_t)n * 512 + j) * 64 + d4);
    *(float4*)(&ks[row][d4]) = v;
  }
  // x-window fp16: 128 c x 18 float4-chunks (cols 0..71, OOB = 0)
  for (int t = tid; t < 128 * 18; t += 512) {
    int c = t / 18;
    int u = t - c * 18;
    int col = 4 * u;
    int j0 = jlo0 + col;
    const float* xp = x + ((size_t)n * 128 + c) * 512;
    float4 v = make_float4(0.f, 0.f, 0.f, 0.f);
    if (j0 >= 0 && j0 + 3 < 512) {
      v = *(const float4*)(xp + j0);
    } else {
      if (j0 + 0 >= 0 && j0 + 0 < 512) v.x = xp[j0 + 0];
      if (j0 + 1 >= 0 && j0 + 1 < 512) v.y = xp[j0 + 1];
      if (j0 + 2 >= 0 && j0 + 2 < 512) v.z = xp[j0 + 2];
      if (j0 + 3 >= 0 && j0 + 3 < 512) v.w = xp[j0 + 3];
    }
    __half2 p01, p23;
    p01.x = __float2half(v.x); p01.y = __float2half(v.y);
    p23.x = __float2half(v.z); p23.y = __float2half(v.w);
    *(__half2*)(xtw + c * 78 + col) = p01;
    *(__half2*)(xtw + c * 78 + col + 2) = p23;
  }
  __syncthreads();

  // ---- Phase A2: scores + softmax + a-write. Wave w -> row w ----
  {
    int r = w;
    int i = i0 + r;
    int j = jlo0 + r + lane;
    bool valid = (j >= 0 && j < 512);
    const float* krow = &ks[r + lane][0];  // stride 68
    float e = 0.f;
#pragma unroll
    for (int d4 = 0; d4 < 64; d4 += 4) {
      float4 kv = *(const float4*)(krow + d4);
      float4 qv = *(const float4*)(&qs[r][d4]);
      float4 wv = *(const float4*)(&was[d4]);
      float h0 = qv.x + kv.x, h1 = qv.y + kv.y;
      float h2 = qv.z + kv.z, h3 = qv.w + kv.w;
      float t0 = 1.f - 2.f * __builtin_amdgcn_rcpf(__expf(2.f * h0) + 1.f);
      float t1 = 1.f - 2.f * __builtin_amdgcn_rcpf(__expf(2.f * h1) + 1.f);
      float t2 = 1.f - 2.f * __builtin_amdgcn_rcpf(__expf(2.f * h2) + 1.f);
      float t3 = 1.f - 2.f * __builtin_amdgcn_rcpf(__expf(2.f * h3) + 1.f);
      e += wv.x * t0 + wv.y * t1 + wv.z * t2 + wv.w * t3;
    }
    e += ba[0];
    if (!valid) e = -1e30f;

    float m = e;
    for (int o = 32; o > 0; o >>= 1) m = fmaxf(m, __shfl_xor(m, o, 64));
    float ex = valid ? __expf(e - m) : 0.f;
    float s = ex;
    for (int o = 32; o > 0; o >>= 1) s += __shfl_xor(s, o, 64);
    avT[r + lane][r] = ex / (s + 1e-6f);  // abs col = r + lane

    float* arow = a + ((size_t)n * 512 + i) * 512;
    int jlo = i - 32;
#pragma unroll
    for (int t = 0; t < 2; t++) {
      int col0 = 4 * lane + 256 * t;
      float4 v;
      { int jr = col0 + 0 - jlo; int jc = min(max(jr, 0), 63); v.x = (jr >= 0 && jr < 64) ? avT[r + jc][r] : 0.f; }
      { int jr = col0 + 1 - jlo; int jc = min(max(jr, 0), 63); v.y = (jr >= 0 && jr < 64) ? avT[r + jc][r] : 0.f; }
      { int jr = col0 + 2 - jlo; int jc = min(max(jr, 0), 63); v.z = (jr >= 0 && jr < 64) ? avT[r + jc][r] : 0.f; }
      { int jr = col0 + 3 - jlo; int jc = min(max(jr, 0), 63); v.w = (jr >= 0 && jr < 64) ? avT[r + jc][r] : 0.f; }
      *(float4*)(arow + col0) = v;
    }
  }
  __syncthreads();

  // ---- Phase B1: band-matmul partials (cols 18g..18g+17, all 8 rows) ----
  {
    int c = tid & 127;
    int g = tid >> 7;  // 0..3
    const __half* xr = xtw + c * 78;
    float acc[8] = {0.f, 0.f, 0.f, 0.f, 0.f, 0.f, 0.f, 0.f};
    int colb = 18 * g;
#pragma unroll
    for (int u = 0; u < 9; u++) {
      int col = colb + 2 * u;
      __half2 xh = *(const __half2*)(xr + col);
      float xv0 = __half2float(__low2half(xh));
      float xv1 = __half2float(__high2half(xh));
      float4 a0lo = *(const float4*)(&avT[col][0]);      // broadcast b128
      float4 a0hi = *(const float4*)(&avT[col][4]);
      float4 a1lo = *(const float4*)(&avT[col + 1][0]);
      float4 a1hi = *(const float4*)(&avT[col + 1][4]);
      acc[0] += a0lo.x * xv0 + a1lo.x * xv1;
      acc[1] += a0lo.y * xv0 + a1lo.y * xv1;
      acc[2] += a0lo.z * xv0 + a1lo.z * xv1;
      acc[3] += a0lo.w * xv0 + a1lo.w * xv1;
      acc[4] += a0hi.x * xv0 + a1hi.x * xv1;
      acc[5] += a0hi.y * xv0 + a1hi.y * xv1;
      acc[6] += a0hi.z * xv0 + a1hi.z * xv1;
      acc[7] += a0hi.w * xv0 + a1hi.w * xv1;
    }
#pragma unroll
    for (int r = 0; r < 8; r++) partB[g][r][c] = acc[r];  // lane-consecutive
  }
  __syncthreads();

  // ---- Phase B-combine: sum partials + exact fp32 residual -> xstT ----
  {
    int c = tid & 127;
    int r = tid >> 7;  // rows r and r+4
    const float* xp = x + ((size_t)n * 128 + c) * 512;
    float s0 = partB[0][r][c] + partB[1][r][c] + partB[2][r][c] + partB[3][r][c];
    float s1 = partB[0][r + 4][c] + partB[1][r + 4][c] +
               partB[2][r + 4][c] + partB[3][r + 4][c];
    xstT[c][r] = s0 + xp[i0 + r];
    xstT[c][r + 4] = s1 + xp[i0 + r + 4];
  }
  __syncthreads();

  // ---- Phase B2: LN0 in place on xstT. Wave w -> row w ----
  {
    float a0 = xstT[lane][w], a1 = xstT[lane + 64][w];
    float s = a0 + a1, s2 = a0 * a0 + a1 * a1;
    for (int o = 32; o > 0; o >>= 1) {
      s += __shfl_xor(s, o, 64);
      s2 += __shfl_xor(s2, o, 64);
    }
    float mu = s * (1.f / 128.f);
    float var = s2 * (1.f / 128.f) - mu * mu;
    float rs = rsqrtf(var + 1e-5f);
    xstT[lane][w] = (a0 - mu) * rs * g0[lane] + be0[lane];
    xstT[lane + 64][w] = (a1 - mu) * rs * g0[lane + 64] + be0[lane + 64];
  }
  __syncthreads();

  // ---- Phase M0: build x2h fp16 [16][136] (rows 8-15 zero) + zero tsth pad.
  //      Zero regions (rows 8-15) disjoint from fill (rows 0-7): no barrier.
  {
    half8_t z = {};
    half8_t* xpad = (half8_t*)(x2h + 8 * 136);       // rows 8..15: 136 chunks
    for (int idx = tid; idx < 136; idx += 512) xpad[idx] = z;
    half8_t* tpad = (half8_t*)(tsth + 8 * 520);      // rows 8..15: 520 chunks
    for (int idx = tid; idx < 520; idx += 512) tpad[idx] = z;
    int c = tid & 127, rr = tid >> 7;                 // rows rr, rr+4
    x2h[rr * 136 + c] = (_Float16)xstT[c][rr];
    x2h[(rr + 4) * 136 + c] = (_Float16)xstT[c][rr + 4];
  }
  __syncthreads();

  // ---- Phase M1: GEMM1 via MFMA. Wave w -> f-tiles 4w..4w+3 ----
  // A: lane: row=l&15, k=ks*32+(l>>4)*8+j  (rows 8-15 zero)
  // D: lane: row=(l>>4)*4+j, col=ft*16+(l&15)  (lanes 0-31 = rows 0-7)
  {
    int l15 = lane & 15, lk = lane >> 4;
    const _Float16* arow = x2h + l15 * 136;
    half8_t afrag[4];
#pragma unroll
    for (int ksi = 0; ksi < 4; ksi++)
      afrag[ksi] = *(const half8_t*)(arow + ksi * 32 + lk * 8);
#pragma unroll
    for (int i = 0; i < 4; i++) {
      int ft = 4 * w + i;
      f32x4_t acc = {0.f, 0.f, 0.f, 0.f};
#pragma unroll
      for (int ksi = 0; ksi < 4; ksi++) {
        half8_t b = *(const half8_t*)(W0p + ((size_t)(ft * 4 + ksi) << 9) + lane * 8);
        acc = __builtin_amdgcn_mfma_f32_16x16x32_f16(afrag[ksi], b, acc, 0, 0, 0);
      }
      if (lane < 32) {
        int fcol = ft * 16 + l15;
        float bb = b0[fcol];
        _Float16* tdst = tsth + (lk * 4) * 520 + fcol;
#pragma unroll
        for (int j = 0; j < 4; j++)
          tdst[j * 520] = (_Float16)fmaxf(acc[j] + bb, 0.f);
      }
    }
  }
  __syncthreads();

  // ---- Phase M2: GEMM2 via MFMA. Wave w -> c-tile w (16 cols), K=512 ----
  {
    int l15 = lane & 15, lk = lane >> 4;
    const _Float16* arow = tsth + l15 * 520;
    f32x4_t acc = {0.f, 0.f, 0.f, 0.f};
#pragma unroll
    for (int ksi = 0; ksi < 16; ksi++) {
      half8_t av = *(const half8_t*)(arow + ksi * 32 + lk * 8);
      half8_t bv = *(const half8_t*)(W1p + ((size_t)(w * 16 + ksi) << 9) + lane * 8);
      acc = __builtin_amdgcn_mfma_f32_16x16x32_f16(av, bv, acc, 0, 0, 0);
    }
    if (lane < 32) {
      int c = w * 16 + l15;
#pragma unroll
      for (int j = 0; j < 4; j++) ys[lk * 4 + j][c] = acc[j];
    }
  }
  __syncthreads();

  // ---- merged bias + residual + LN1 -> back into xstT ----
  {
    float a0 = ys[w][lane] + b1[lane] + xstT[lane][w];
    float a1 = ys[w][lane + 64] + b1[lane + 64] + xstT[lane + 64][w];
    float s = a0 + a1, s2 = a0 * a0 + a1 * a1;
    for (int o = 32; o > 0; o >>= 1) {
      s += __shfl_xor(s, o, 64);
      s2 += __shfl_xor(s2, o, 64);
    }
    float mu = s * (1.f / 128.f);
    float var = s2 * (1.f / 128.f) - mu * mu;
    float rs = rsqrtf(var + 1e-5f);
    xstT[lane][w] = (a0 - mu) * rs * g1[lane] + be1[lane];       // RMW own slot
    xstT[lane + 64][w] = (a1 - mu) * rs * g1[lane + 64] + be1[lane + 64];
  }
  __syncthreads();

  // ---- transposed write: out (N,C,L); 8 consecutive l per c ----
  {
    int c = tid >> 2, tq = tid & 3;
    *(float2*)(out + ((size_t)n * 128 + c) * 512 + i0 + 2 * tq) =
        make_float2(xstT[c][2 * tq], xstT[c][2 * tq + 1]);
  }
}

// ---------------------------------------------------------------------------
extern "C" void kernel_launch(void* const* d_in, const int* in_sizes, int n_in,
                              void* d_out, int out_size, void* d_ws, size_t ws_size,
                              hipStream_t stream) {
  const float* x   = (const float*)d_in[0];
  const float* Wx  = (const float*)d_in[1];
  const float* Wt  = (const float*)d_in[2];
  const float* bh  = (const float*)d_in[3];
  const float* Wa  = (const float*)d_in[4];
  const float* ba  = (const float*)d_in[5];
  const float* W0  = (const float*)d_in[6];
  const float* b0  = (const float*)d_in[7];
  const float* W1  = (const float*)d_in[8];
  const float* b1  = (const float*)d_in[9];
  const float* g0  = (const float*)d_in[10];
  const float* be0 = (const float*)d_in[11];
  const float* g1  = (const float*)d_in[12];
  const float* be1 = (const float*)d_in[13];

  float* outx = (float*)d_out;           // N*C*L = 524288
  float* outa = outx + (size_t)524288;   // N*L*L = 2097152

  float* ws = (float*)d_ws;
  float* q  = ws;                        // 262144 floats
  float* k  = q + 262144;                // 262144 floats
  _Float16* W0p = (_Float16*)(k + 262144);  // 65536 halves (128 KB)
  _Float16* W1p = W0p + 65536;              // 65536 halves (128 KB)

  prep_kernel<<<256, 512, 0, stream>>>(x, Wt, Wx, W0, W1, q, k, W0p, W1p);
  attn_ffn_fused_kernel<<<512, 512, 0, stream>>>(
      x, q, k, bh, Wa, ba, g0, be0, W0p, b0, W1p, b1, g1, be1, outa, outx);
}